// Round 1
// baseline (84.068 us; speedup 1.0000x reference)
//
#include <hip/hip_runtime.h>
#include <hip/hip_bf16.h>
#include <math.h>

typedef __attribute__((ext_vector_type(8))) __bf16 bf16x8;
typedef __attribute__((ext_vector_type(2))) __bf16 bf16x2;
typedef __attribute__((ext_vector_type(4))) float f32x4;

#define NPTS 1024
#define CIN 512
#define NSAMP 64
#define LDA2 264
#define LDF 264

// Exact-order f32 local-coords to match numpy ref rounding (no FMA contraction):
__device__ __forceinline__ void local_coords(const float* q, float cx, float cy, float cz,
                                             const float R[9], float& l0, float& l1, float& l2) {
    float d0 = __fsub_rn(q[0], cx);
    float d1 = __fsub_rn(q[1], cy);
    float d2 = __fsub_rn(q[2], cz);
    l0 = __fadd_rn(__fadd_rn(__fmul_rn(d0, R[0]), __fmul_rn(d1, R[3])), __fmul_rn(d2, R[6]));
    l1 = __fadd_rn(__fadd_rn(__fmul_rn(d0, R[1]), __fmul_rn(d1, R[4])), __fmul_rn(d2, R[7]));
    l2 = __fadd_rn(__fadd_rn(__fmul_rn(d0, R[2]), __fmul_rn(d1, R[5])), __fmul_rn(d2, R[8]));
}

// ---------------- prep: weights->bf16, BN fold, xyz-weight extract ----------------
__global__ void prep_kernel(const float* __restrict__ W1, const float* __restrict__ W2,
                            const float* __restrict__ g1, const float* __restrict__ be1,
                            const float* __restrict__ m1, const float* __restrict__ v1,
                            const float* __restrict__ g2, const float* __restrict__ be2,
                            const float* __restrict__ m2, const float* __restrict__ v2,
                            __bf16* __restrict__ W1f, __bf16* __restrict__ W2b,
                            float* __restrict__ wx,
                            float* __restrict__ s1, float* __restrict__ b1,
                            float* __restrict__ s2, float* __restrict__ b2) {
    const int o = blockIdx.x;
    const int t = threadIdx.x;
    if (t == 0) {
        float sc1 = g1[o] / sqrtf(v1[o] + 1e-5f);
        s1[o] = sc1;
        b1[o] = be1[o] - m1[o] * sc1;
        float sc2 = g2[o] / sqrtf(v2[o] + 1e-5f);
        s2[o] = sc2;
        b2[o] = be2[o] - m2[o] * sc2;
        wx[o * 4 + 0] = W1[o * 515 + 0];
        wx[o * 4 + 1] = W1[o * 515 + 1];
        wx[o * 4 + 2] = W1[o * 515 + 2];
        wx[o * 4 + 3] = 0.f;
    }
    for (int k = t; k < CIN; k += blockDim.x)
        W1f[o * CIN + k] = (__bf16)W1[o * 515 + 3 + k];
    for (int k = t; k < 256; k += blockDim.x)
        W2b[o * 256 + k] = (__bf16)W2[o * 256 + k];
}

// ---------------- F-GEMM: F[b][n][o] = sum_c feats[b][c][n] * W1[o][3+c] ----------------
__global__ __launch_bounds__(256) void fgemm_kernel(const float* __restrict__ feats,
                                                    const __bf16* __restrict__ W1f,
                                                    float* __restrict__ F) {
    __shared__ __align__(16) __bf16 Ft[64][LDF];  // transposed feats tile [n_local][c_local]
    const int t = threadIdx.x;
    const int b = blockIdx.x >> 4;
    const int n0 = (blockIdx.x & 15) << 6;
    const int l = t & 63, w = t >> 6;
    const int lo = l & 15, kg = l >> 4;

    f32x4 acc[4][4];
#pragma unroll
    for (int mt = 0; mt < 4; ++mt)
#pragma unroll
        for (int nt = 0; nt < 4; ++nt)
            acc[mt][nt] = f32x4{0.f, 0.f, 0.f, 0.f};

    const float* fb = feats + (size_t)b * (CIN * NPTS) + n0;

    for (int half = 0; half < 2; ++half) {
        __syncthreads();  // protect Ft from previous half's readers
        // stage 256 c-values x 64 n, transposed, pairwise b32 writes
        {
            const int q = t >> 6;  // 0..3
            for (int i = 0; i < 32; ++i) {
                int cl = (q * 32 + i) * 2;          // local c (even)
                int c = half * 256 + cl;            // absolute c
                float v0 = fb[(size_t)c * NPTS + l];
                float v1 = fb[(size_t)(c + 1) * NPTS + l];
                bf16x2 pk = {(__bf16)v0, (__bf16)v1};
                *(bf16x2*)(&Ft[l][cl]) = pk;
            }
        }
        __syncthreads();
#pragma unroll
        for (int ks = 0; ks < 8; ++ks) {
            const int kk = ks * 32 + kg * 8;
            bf16x8 bfr[4];
#pragma unroll
            for (int nt = 0; nt < 4; ++nt)
                bfr[nt] = *(const bf16x8*)(&Ft[nt * 16 + lo][kk]);
#pragma unroll
            for (int mt = 0; mt < 4; ++mt) {
                const int o = w * 64 + mt * 16 + lo;
                bf16x8 af = *(const bf16x8*)(&W1f[(size_t)o * CIN + half * 256 + kk]);
#pragma unroll
                for (int nt = 0; nt < 4; ++nt)
                    acc[mt][nt] = __builtin_amdgcn_mfma_f32_16x16x32_bf16(af, bfr[nt], acc[mt][nt], 0, 0, 0);
            }
        }
    }
    // store: D row = o-local = (lane>>4)*4+r, col = n-local = lane&15
#pragma unroll
    for (int mt = 0; mt < 4; ++mt)
#pragma unroll
        for (int nt = 0; nt < 4; ++nt)
#pragma unroll
            for (int r = 0; r < 4; ++r) {
                const int o = w * 64 + mt * 16 + kg * 4 + r;
                const int n = n0 + nt * 16 + lo;
                F[((size_t)(b * NPTS + n)) * 256 + o] = acc[mt][nt][r];
            }
}

// ---------------- fused: selection + A2 build + GEMM2 + BN2 + max ----------------
__global__ __launch_bounds__(256, 2) void fused_kernel(
    const float* __restrict__ xyz, const float* __restrict__ rot,
    const float* __restrict__ crop, const float* __restrict__ F,
    const float* __restrict__ wx, const float* __restrict__ s1g, const float* __restrict__ b1g,
    const __bf16* __restrict__ W2b, const float* __restrict__ s2g, const float* __restrict__ b2g,
    float* __restrict__ out) {
    __shared__ __align__(16) __bf16 A2[NSAMP][LDA2];
    __shared__ f32x4 wx_l[256];
    __shared__ float sbn_s[256];
    __shared__ float sbn_b[256];
    __shared__ unsigned long long msk[16];
    __shared__ int sel[NSAMP];
    __shared__ int wpre[17];

    const int bid = blockIdx.x;
    const int b = bid >> 10;
    const int p = bid & 1023;
    const int t = threadIdx.x;
    const int l = t & 63, w = t >> 6;
    const int lo = l & 15, kg = l >> 4;

    // stage BN1 params + xyz weights (ready well before use; covered by later syncs)
    wx_l[t] = ((const f32x4*)wx)[t];
    sbn_s[t] = s1g[t];
    sbn_b[t] = b1g[t];

    const float cx = xyz[bid * 3 + 0], cy = xyz[bid * 3 + 1], cz = xyz[bid * 3 + 2];
    float R[9];
#pragma unroll
    for (int j = 0; j < 9; ++j) R[j] = rot[bid * 9 + j];
    const float h0 = 0.5f * crop[bid * 3 + 0];
    const float h1 = 0.5f * crop[bid * 3 + 1];
    const float h2 = 0.5f * crop[bid * 3 + 2];

    // inside mask for all 1024 points
#pragma unroll
    for (int i = 0; i < 4; ++i) {
        const int n = i * 256 + t;
        float l0, l1, l2;
        local_coords(xyz + (size_t)(b * NPTS + n) * 3, cx, cy, cz, R, l0, l1, l2);
        bool ins = (__builtin_fabsf(l0) <= h0) && (__builtin_fabsf(l1) <= h1) &&
                   (__builtin_fabsf(l2) <= h2);
        unsigned long long bal = __ballot(ins);
        if (l == 0) msk[i * 4 + w] = bal;
    }
    __syncthreads();
    if (t == 0) {
        int a = 0;
#pragma unroll
        for (int k = 0; k < 16; ++k) { wpre[k] = a; a += __popcll(msk[k]); }
        wpre[16] = a;
    }
    __syncthreads();
    const int cnt = wpre[16];
    // stable first-64 selection
#pragma unroll
    for (int i = 0; i < 4; ++i) {
        const int n = i * 256 + t;
        const unsigned long long wd = msk[n >> 6];
        const int bit = n & 63;
        if ((wd >> bit) & 1ull) {
            int rank = wpre[n >> 6] + __popcll(wd & ((1ull << bit) - 1ull));
            if (rank < NSAMP) sel[rank] = n;
        }
    }
    __syncthreads();
    if (t < NSAMP && t >= cnt) sel[t] = (cnt > 0) ? sel[0] : 0;
    __syncthreads();

    // A2[s][o] = relu(BN1(F[n_s][o] + local(s)·W1xyz[o])) in bf16
    {
        const int s = t >> 2, cg = t & 3;
        const int n = sel[s];
        float l0, l1, l2;
        local_coords(xyz + (size_t)(b * NPTS + n) * 3, cx, cy, cz, R, l0, l1, l2);
        const float* Fb = F + ((size_t)(b * NPTS + n)) * 256;
#pragma unroll
        for (int ci = 0; ci < 8; ++ci) {
            const int cc = (ci + cg * 2) & 7;  // stagger to avoid LDS write conflicts
            const int o8 = cg * 64 + cc * 8;
            const f32x4 f0 = *(const f32x4*)(Fb + o8);
            const f32x4 f1 = *(const f32x4*)(Fb + o8 + 4);
            bf16x8 pk;
#pragma unroll
            for (int j = 0; j < 8; ++j) {
                const int o = o8 + j;
                const f32x4 wv = wx_l[o];
                const float fj = (j < 4) ? f0[j] : f1[j - 4];
                const float x = fmaf(l0, wv.x, fmaf(l1, wv.y, l2 * wv.z));
                const float y = fmaxf(fmaf(fj + x, sbn_s[o], sbn_b[o]), 0.f);
                pk[j] = (__bf16)y;
            }
            *(bf16x8*)(&A2[s][o8]) = pk;
        }
    }
    __syncthreads();

    // GEMM2: h2[s][o] = sum_k A2[s][k] * W2[o][k]
    f32x4 acc[4][4];
#pragma unroll
    for (int mt = 0; mt < 4; ++mt)
#pragma unroll
        for (int nt = 0; nt < 4; ++nt)
            acc[mt][nt] = f32x4{0.f, 0.f, 0.f, 0.f};

    const int ob = w * 64;
#pragma unroll
    for (int ks = 0; ks < 8; ++ks) {
        const int kk = ks * 32 + kg * 8;
        bf16x8 af[4];
#pragma unroll
        for (int mt = 0; mt < 4; ++mt)
            af[mt] = *(const bf16x8*)(&A2[mt * 16 + lo][kk]);
#pragma unroll
        for (int nt = 0; nt < 4; ++nt) {
            const int o = ob + nt * 16 + lo;
            const bf16x8 bfr = *(const bf16x8*)(&W2b[(size_t)o * 256 + kk]);
#pragma unroll
            for (int mt = 0; mt < 4; ++mt)
                acc[mt][nt] = __builtin_amdgcn_mfma_f32_16x16x32_bf16(af[mt], bfr, acc[mt][nt], 0, 0, 0);
        }
    }

    // BN2 + relu + max over 64 samples + store out[b][o][p]
#pragma unroll
    for (int nt = 0; nt < 4; ++nt) {
        const int o = ob + nt * 16 + lo;
        const float sc = s2g[o], bb = b2g[o];
        float mx = 0.f;  // relu output >= 0
#pragma unroll
        for (int mt = 0; mt < 4; ++mt)
#pragma unroll
            for (int r = 0; r < 4; ++r)
                mx = fmaxf(mx, fmaxf(fmaf(acc[mt][nt][r], sc, bb), 0.f));
        mx = fmaxf(mx, __shfl_xor(mx, 16));
        mx = fmaxf(mx, __shfl_xor(mx, 32));
        if (kg == 0)
            out[(size_t)b * (256 * NPTS) + (size_t)o * NPTS + p] = mx;
    }
}

extern "C" void kernel_launch(void* const* d_in, const int* in_sizes, int n_in,
                              void* d_out, int out_size, void* d_ws, size_t ws_size,
                              hipStream_t stream) {
    (void)in_sizes; (void)n_in; (void)out_size; (void)ws_size;
    const float* xyz   = (const float*)d_in[0];
    const float* feats = (const float*)d_in[1];
    const float* rot   = (const float*)d_in[2];
    const float* crop  = (const float*)d_in[3];
    const float* W1    = (const float*)d_in[4];
    const float* g1    = (const float*)d_in[5];
    const float* be1   = (const float*)d_in[6];
    const float* m1    = (const float*)d_in[7];
    const float* v1    = (const float*)d_in[8];
    const float* W2    = (const float*)d_in[9];
    const float* g2    = (const float*)d_in[10];
    const float* be2   = (const float*)d_in[11];
    const float* m2    = (const float*)d_in[12];
    const float* v2    = (const float*)d_in[13];

    char* ws = (char*)d_ws;
    __bf16* W1f = (__bf16*)(ws + 0);        // 256*512*2  = 262144
    __bf16* W2b = (__bf16*)(ws + 262144);   // 256*256*2  = 131072
    float*  wx  = (float*)(ws + 393216);    // 256*4*4    = 4096
    float*  s1  = (float*)(ws + 397312);
    float*  b1  = (float*)(ws + 398336);
    float*  s2  = (float*)(ws + 399360);
    float*  b2  = (float*)(ws + 400384);
    float*  F   = (float*)(ws + 401408);    // 2*1024*256*4 = 2097152

    prep_kernel<<<256, 256, 0, stream>>>(W1, W2, g1, be1, m1, v1, g2, be2, m2, v2,
                                         W1f, W2b, wx, s1, b1, s2, b2);
    fgemm_kernel<<<32, 256, 0, stream>>>(feats, W1f, F);
    fused_kernel<<<2048, 256, 0, stream>>>(xyz, rot, crop, F, wx, s1, b1, W2b, s2, b2,
                                           (float*)d_out);
}

// Round 2
// 74.069 us; speedup vs baseline: 1.1350x; 1.1350x over previous
//
#include <hip/hip_runtime.h>
#include <hip/hip_bf16.h>
#include <math.h>

typedef __attribute__((ext_vector_type(8))) __bf16 bf16x8;
typedef __attribute__((ext_vector_type(2))) __bf16 bf16x2;
typedef __attribute__((ext_vector_type(4))) float f32x4;

#define NPTS 1024
#define CIN 512
#define NSAMP 64
#define LDA2 264   // bf16 per A2 row: 256 + 8 pad -> row stride 132 dw == 4 mod 32
#define LDFT 520   // bf16 per Ft row: 512 + 8 pad
#define LDFO 260   // f32 per Fo row: 256 + 4 pad

// Exact-order f32 local-coords to match numpy ref rounding (no FMA contraction):
__device__ __forceinline__ void local_coords(const float* q, float cx, float cy, float cz,
                                             const float R[9], float& l0, float& l1, float& l2) {
    float d0 = __fsub_rn(q[0], cx);
    float d1 = __fsub_rn(q[1], cy);
    float d2 = __fsub_rn(q[2], cz);
    l0 = __fadd_rn(__fadd_rn(__fmul_rn(d0, R[0]), __fmul_rn(d1, R[3])), __fmul_rn(d2, R[6]));
    l1 = __fadd_rn(__fadd_rn(__fmul_rn(d0, R[1]), __fmul_rn(d1, R[4])), __fmul_rn(d2, R[7]));
    l2 = __fadd_rn(__fadd_rn(__fmul_rn(d0, R[2]), __fmul_rn(d1, R[5])), __fmul_rn(d2, R[8]));
}

// ---------------- prep: weights->bf16, BN fold, scaled xyz-weight extract ----------------
__global__ void prep_kernel(const float* __restrict__ W1, const float* __restrict__ W2,
                            const float* __restrict__ g1, const float* __restrict__ be1,
                            const float* __restrict__ m1, const float* __restrict__ v1,
                            const float* __restrict__ g2, const float* __restrict__ be2,
                            const float* __restrict__ m2, const float* __restrict__ v2,
                            __bf16* __restrict__ W1f, __bf16* __restrict__ W2b,
                            float* __restrict__ wxs,
                            float* __restrict__ s1, float* __restrict__ b1,
                            float* __restrict__ s2, float* __restrict__ b2) {
    const int o = blockIdx.x;
    const int t = threadIdx.x;
    if (t == 0) {
        float sc1 = g1[o] / sqrtf(v1[o] + 1e-5f);
        s1[o] = sc1;
        b1[o] = be1[o] - m1[o] * sc1;
        float sc2 = g2[o] / sqrtf(v2[o] + 1e-5f);
        s2[o] = sc2;
        b2[o] = be2[o] - m2[o] * sc2;
        wxs[o * 4 + 0] = sc1 * W1[o * 515 + 0];
        wxs[o * 4 + 1] = sc1 * W1[o * 515 + 1];
        wxs[o * 4 + 2] = sc1 * W1[o * 515 + 2];
        wxs[o * 4 + 3] = 0.f;
    }
    for (int k = t; k < CIN; k += blockDim.x)
        W1f[o * CIN + k] = (__bf16)W1[o * 515 + 3 + k];
    for (int k = t; k < 256; k += blockDim.x)
        W2b[o * 256 + k] = (__bf16)W2[o * 256 + k];
}

// ------- F-GEMM: Fs[b][n][o] = s1[o] * (sum_c feats[b][c][n] * W1f[o][c]) + b1[o] -------
// 128 blocks: b = bid>>6, n-tile of 16 = (bid&63). Wave w owns o in [64w, 64w+64).
__global__ __launch_bounds__(256) void fgemm_kernel(const float* __restrict__ feats,
                                                    const __bf16* __restrict__ W1f,
                                                    const float* __restrict__ s1,
                                                    const float* __restrict__ b1,
                                                    float* __restrict__ Fs) {
    __shared__ __align__(16) __bf16 Ft[16][LDFT];  // [n_local][c]
    __shared__ __align__(16) float Fo[16][LDFO];   // [n_local][o] staging for coalesced store
    const int t = threadIdx.x;
    const int b = blockIdx.x >> 6;
    const int n0 = (blockIdx.x & 63) << 4;
    const int l = t & 63, w = t >> 6;
    const int lo = l & 15, kg = l >> 4;

    const float* fb = feats + (size_t)b * (CIN * NPTS) + n0;

    // stage all 512 c x 16 n, transposed, bf16x2 writes
    {
        const int n = t & 15;
        const int cq = (t >> 4) * 2;  // 0,2,..,30
        for (int i = 0; i < 16; ++i) {
            int c = i * 32 + cq;
            float v0 = fb[(size_t)c * NPTS + n];
            float v1 = fb[(size_t)(c + 1) * NPTS + n];
            bf16x2 pk = {(__bf16)v0, (__bf16)v1};
            *(bf16x2*)(&Ft[n][c]) = pk;
        }
    }
    __syncthreads();

    f32x4 acc[4];
#pragma unroll
    for (int mt = 0; mt < 4; ++mt) acc[mt] = f32x4{0.f, 0.f, 0.f, 0.f};

#pragma unroll
    for (int ks = 0; ks < 16; ++ks) {
        const int kk = ks * 32 + kg * 8;
        const bf16x8 bfr = *(const bf16x8*)(&Ft[lo][kk]);
#pragma unroll
        for (int mt = 0; mt < 4; ++mt) {
            const int o = w * 64 + mt * 16 + lo;
            const bf16x8 af = *(const bf16x8*)(&W1f[(size_t)o * CIN + kk]);
            acc[mt] = __builtin_amdgcn_mfma_f32_16x16x32_bf16(af, bfr, acc[mt], 0, 0, 0);
        }
    }
    __syncthreads();
    // BN1-fold into Fo[n][o]; D: col = n_local = lo, row = kg*4 + r
#pragma unroll
    for (int mt = 0; mt < 4; ++mt) {
        const int ob = w * 64 + mt * 16 + kg * 4;
        const f32x4 sv = *(const f32x4*)(&s1[ob]);
        const f32x4 bv = *(const f32x4*)(&b1[ob]);
        f32x4 r;
#pragma unroll
        for (int j = 0; j < 4; ++j) r[j] = fmaf(acc[mt][j], sv[j], bv[j]);
        *(f32x4*)(&Fo[lo][ob]) = r;
    }
    __syncthreads();
    // coalesced store: 16 rows x 1KB
    {
        const int row = t >> 4, c = t & 15;
#pragma unroll
        for (int pass = 0; pass < 4; ++pass) {
            const int col = c * 4 + pass * 64;
            const f32x4 v = *(const f32x4*)(&Fo[row][col]);
            *(f32x4*)(&Fs[((size_t)(b * NPTS + n0 + row)) * 256 + col]) = v;
        }
    }
}

// ---------------- fused: selection + A2 build + GEMM2 + BN2 + max ----------------
__global__ __launch_bounds__(256, 4) void fused_kernel(
    const float* __restrict__ xyz, const float* __restrict__ rot,
    const float* __restrict__ crop, const float* __restrict__ Fs,
    const float* __restrict__ wxs,
    const __bf16* __restrict__ W2b, const float* __restrict__ s2g, const float* __restrict__ b2g,
    float* __restrict__ out) {
    __shared__ __align__(16) __bf16 A2[NSAMP][LDA2];
    __shared__ unsigned long long msk[16];
    __shared__ int sel[NSAMP];
    __shared__ int wpre[17];

    // XCD-chunked bijective swizzle (2048 = 8 * 256)
    const int bid = ((int)blockIdx.x & 7) * 256 + ((int)blockIdx.x >> 3);
    const int b = bid >> 10;
    const int p = bid & 1023;
    const int t = threadIdx.x;
    const int l = t & 63, w = t >> 6;
    const int lo = l & 15, kg = l >> 4;

    const float cx = xyz[bid * 3 + 0], cy = xyz[bid * 3 + 1], cz = xyz[bid * 3 + 2];
    float R[9];
#pragma unroll
    for (int j = 0; j < 9; ++j) R[j] = rot[bid * 9 + j];
    const float h0 = 0.5f * crop[bid * 3 + 0];
    const float h1 = 0.5f * crop[bid * 3 + 1];
    const float h2 = 0.5f * crop[bid * 3 + 2];

    // inside mask for all 1024 points
#pragma unroll
    for (int i = 0; i < 4; ++i) {
        const int n = i * 256 + t;
        float l0, l1, l2;
        local_coords(xyz + (size_t)(b * NPTS + n) * 3, cx, cy, cz, R, l0, l1, l2);
        bool ins = (__builtin_fabsf(l0) <= h0) && (__builtin_fabsf(l1) <= h1) &&
                   (__builtin_fabsf(l2) <= h2);
        unsigned long long bal = __ballot(ins);
        if (l == 0) msk[i * 4 + w] = bal;
    }
    __syncthreads();
    if (t == 0) {
        int a = 0;
#pragma unroll
        for (int k = 0; k < 16; ++k) { wpre[k] = a; a += __popcll(msk[k]); }
        wpre[16] = a;
    }
    __syncthreads();
    const int cnt = wpre[16];
    // stable first-64 selection
#pragma unroll
    for (int i = 0; i < 4; ++i) {
        const int n = i * 256 + t;
        const unsigned long long wd = msk[n >> 6];
        const int bit = n & 63;
        if ((wd >> bit) & 1ull) {
            int rank = wpre[n >> 6] + __popcll(wd & ((1ull << bit) - 1ull));
            if (rank < NSAMP) sel[rank] = n;
        }
    }
    __syncthreads();
    const int sel0 = (cnt > 0) ? sel[0] : 0;

    // A2[s][o] = relu(Fs[n_s][o] + local(s)·wxs[o]) in bf16
    // thread <- (o-chunk of 8) x (8 s values); weights cached in registers
    {
        const int oc = (t & 31) * 8;
        const int sbase = (t >> 5) * 8;
        f32x4 wv[8];
#pragma unroll
        for (int j = 0; j < 8; ++j) wv[j] = *(const f32x4*)(&wxs[(oc + j) * 4]);
#pragma unroll
        for (int si = 0; si < 8; ++si) {
            const int s = sbase + si;
            const int n = (s < cnt) ? sel[s] : sel0;
            float l0, l1, l2;
            local_coords(xyz + (size_t)(b * NPTS + n) * 3, cx, cy, cz, R, l0, l1, l2);
            const float* Fr = Fs + ((size_t)(b * NPTS + n)) * 256 + oc;
            const f32x4 f0 = *(const f32x4*)(Fr);
            const f32x4 f1 = *(const f32x4*)(Fr + 4);
            bf16x8 pk;
#pragma unroll
            for (int j = 0; j < 8; ++j) {
                const float fj = (j < 4) ? f0[j] : f1[j - 4];
                const float x = fmaf(l0, wv[j].x, fmaf(l1, wv[j].y, fmaf(l2, wv[j].z, fj)));
                pk[j] = (__bf16)fmaxf(x, 0.f);
            }
            *(bf16x8*)(&A2[s][oc]) = pk;
        }
    }
    __syncthreads();

    // GEMM2: h2[s][o] = sum_k A2[s][k] * W2[o][k]
    f32x4 acc[4][4];
#pragma unroll
    for (int mt = 0; mt < 4; ++mt)
#pragma unroll
        for (int nt = 0; nt < 4; ++nt)
            acc[mt][nt] = f32x4{0.f, 0.f, 0.f, 0.f};

    const int ob = w * 64;
#pragma unroll
    for (int ks = 0; ks < 8; ++ks) {
        const int kk = ks * 32 + kg * 8;
        bf16x8 af[4];
#pragma unroll
        for (int mt = 0; mt < 4; ++mt)
            af[mt] = *(const bf16x8*)(&A2[mt * 16 + lo][kk]);
#pragma unroll
        for (int nt = 0; nt < 4; ++nt) {
            const int o = ob + nt * 16 + lo;
            const bf16x8 bfr = *(const bf16x8*)(&W2b[(size_t)o * 256 + kk]);
#pragma unroll
            for (int mt = 0; mt < 4; ++mt)
                acc[mt][nt] = __builtin_amdgcn_mfma_f32_16x16x32_bf16(af[mt], bfr, acc[mt][nt], 0, 0, 0);
        }
    }

    // BN2 + relu + max over 64 samples + store out[b][o][p]
#pragma unroll
    for (int nt = 0; nt < 4; ++nt) {
        const int o = ob + nt * 16 + lo;
        const float sc = s2g[o], bb = b2g[o];
        float mx = 0.f;  // relu output >= 0
#pragma unroll
        for (int mt = 0; mt < 4; ++mt)
#pragma unroll
            for (int r = 0; r < 4; ++r)
                mx = fmaxf(mx, fmaxf(fmaf(acc[mt][nt][r], sc, bb), 0.f));
        mx = fmaxf(mx, __shfl_xor(mx, 16));
        mx = fmaxf(mx, __shfl_xor(mx, 32));
        if (kg == 0)
            out[(size_t)b * (256 * NPTS) + (size_t)o * NPTS + p] = mx;
    }
}

extern "C" void kernel_launch(void* const* d_in, const int* in_sizes, int n_in,
                              void* d_out, int out_size, void* d_ws, size_t ws_size,
                              hipStream_t stream) {
    (void)in_sizes; (void)n_in; (void)out_size; (void)ws_size;
    const float* xyz   = (const float*)d_in[0];
    const float* feats = (const float*)d_in[1];
    const float* rot   = (const float*)d_in[2];
    const float* crop  = (const float*)d_in[3];
    const float* W1    = (const float*)d_in[4];
    const float* g1    = (const float*)d_in[5];
    const float* be1   = (const float*)d_in[6];
    const float* m1    = (const float*)d_in[7];
    const float* v1    = (const float*)d_in[8];
    const float* W2    = (const float*)d_in[9];
    const float* g2    = (const float*)d_in[10];
    const float* be2   = (const float*)d_in[11];
    const float* m2    = (const float*)d_in[12];
    const float* v2    = (const float*)d_in[13];

    char* ws = (char*)d_ws;
    __bf16* W1f = (__bf16*)(ws + 0);        // 256*512*2  = 262144
    __bf16* W2b = (__bf16*)(ws + 262144);   // 256*256*2  = 131072
    float*  wxs = (float*)(ws + 393216);    // 256*4*4    = 4096
    float*  s1  = (float*)(ws + 397312);
    float*  b1  = (float*)(ws + 398336);
    float*  s2  = (float*)(ws + 399360);
    float*  b2  = (float*)(ws + 400384);
    float*  Fs  = (float*)(ws + 401408);    // 2*1024*256*4 = 2097152

    prep_kernel<<<256, 256, 0, stream>>>(W1, W2, g1, be1, m1, v1, g2, be2, m2, v2,
                                         W1f, W2b, wxs, s1, b1, s2, b2);
    fgemm_kernel<<<128, 256, 0, stream>>>(feats, W1f, s1, b1, Fs);
    fused_kernel<<<2048, 256, 0, stream>>>(xyz, rot, crop, Fs, wxs, W2b, s2, b2,
                                           (float*)d_out);
}

// Round 3
// 66.715 us; speedup vs baseline: 1.2601x; 1.1102x over previous
//
#include <hip/hip_runtime.h>
#include <hip/hip_bf16.h>
#include <math.h>

typedef __attribute__((ext_vector_type(8))) __bf16 bf16x8;
typedef __attribute__((ext_vector_type(2))) __bf16 bf16x2;
typedef __attribute__((ext_vector_type(4))) float f32x4;

#define NPTS 1024
#define CIN 512
#define NSAMP 64
#define LDA2 264   // bf16 per A2 row: 256 + 8 pad
#define LDFT 520   // bf16 per Ft row: 512 + 8 pad
#define LDFO 260   // f32 per Fo row: 256 + 4 pad

// Exact-order f32 local-coords to match numpy ref rounding (no FMA contraction):
__device__ __forceinline__ void local_coords(const float* q, float cx, float cy, float cz,
                                             const float R[9], float& l0, float& l1, float& l2) {
    float d0 = __fsub_rn(q[0], cx);
    float d1 = __fsub_rn(q[1], cy);
    float d2 = __fsub_rn(q[2], cz);
    l0 = __fadd_rn(__fadd_rn(__fmul_rn(d0, R[0]), __fmul_rn(d1, R[3])), __fmul_rn(d2, R[6]));
    l1 = __fadd_rn(__fadd_rn(__fmul_rn(d0, R[1]), __fmul_rn(d1, R[4])), __fmul_rn(d2, R[7]));
    l2 = __fadd_rn(__fadd_rn(__fmul_rn(d0, R[2]), __fmul_rn(d1, R[5])), __fmul_rn(d2, R[8]));
}

// ---------------- prep: weights->bf16, BN fold, scaled xyz-weight extract ----------------
__global__ void prep_kernel(const float* __restrict__ W1, const float* __restrict__ W2,
                            const float* __restrict__ g1, const float* __restrict__ be1,
                            const float* __restrict__ m1, const float* __restrict__ v1,
                            const float* __restrict__ g2, const float* __restrict__ be2,
                            const float* __restrict__ m2, const float* __restrict__ v2,
                            __bf16* __restrict__ W1f, __bf16* __restrict__ W2b,
                            float* __restrict__ wxs,
                            float* __restrict__ s1, float* __restrict__ b1,
                            float* __restrict__ s2, float* __restrict__ b2) {
    const int o = blockIdx.x;
    const int t = threadIdx.x;
    if (t == 0) {
        float sc1 = g1[o] / sqrtf(v1[o] + 1e-5f);
        s1[o] = sc1;
        b1[o] = be1[o] - m1[o] * sc1;
        float sc2 = g2[o] / sqrtf(v2[o] + 1e-5f);
        s2[o] = sc2;
        b2[o] = be2[o] - m2[o] * sc2;
        wxs[o * 4 + 0] = sc1 * W1[o * 515 + 0];
        wxs[o * 4 + 1] = sc1 * W1[o * 515 + 1];
        wxs[o * 4 + 2] = sc1 * W1[o * 515 + 2];
        wxs[o * 4 + 3] = 0.f;
    }
    for (int k = t; k < CIN; k += blockDim.x)
        W1f[o * CIN + k] = (__bf16)W1[o * 515 + 3 + k];
    for (int k = t; k < 256; k += blockDim.x)
        W2b[o * 256 + k] = (__bf16)W2[o * 256 + k];
}

// ------- F-GEMM: Fs[b][n][o] = s1[o] * (sum_c feats[b][c][n] * W1f[o][c]) + b1[o] -------
__global__ __launch_bounds__(256) void fgemm_kernel(const float* __restrict__ feats,
                                                    const __bf16* __restrict__ W1f,
                                                    const float* __restrict__ s1,
                                                    const float* __restrict__ b1,
                                                    float* __restrict__ Fs) {
    __shared__ __align__(16) __bf16 Ft[16][LDFT];  // [n_local][c]
    __shared__ __align__(16) float Fo[16][LDFO];   // [n_local][o] staging for coalesced store
    const int t = threadIdx.x;
    const int b = blockIdx.x >> 6;
    const int n0 = (blockIdx.x & 63) << 4;
    const int l = t & 63, w = t >> 6;
    const int lo = l & 15, kg = l >> 4;

    const float* fb = feats + (size_t)b * (CIN * NPTS) + n0;

    // stage all 512 c x 16 n, transposed, bf16x2 writes
    {
        const int n = t & 15;
        const int cq = (t >> 4) * 2;  // 0,2,..,30
        for (int i = 0; i < 16; ++i) {
            int c = i * 32 + cq;
            float v0 = fb[(size_t)c * NPTS + n];
            float v1 = fb[(size_t)(c + 1) * NPTS + n];
            bf16x2 pk = {(__bf16)v0, (__bf16)v1};
            *(bf16x2*)(&Ft[n][c]) = pk;
        }
    }
    __syncthreads();

    f32x4 acc[4];
#pragma unroll
    for (int mt = 0; mt < 4; ++mt) acc[mt] = f32x4{0.f, 0.f, 0.f, 0.f};

#pragma unroll
    for (int ks = 0; ks < 16; ++ks) {
        const int kk = ks * 32 + kg * 8;
        const bf16x8 bfr = *(const bf16x8*)(&Ft[lo][kk]);
#pragma unroll
        for (int mt = 0; mt < 4; ++mt) {
            const int o = w * 64 + mt * 16 + lo;
            const bf16x8 af = *(const bf16x8*)(&W1f[(size_t)o * CIN + kk]);
            acc[mt] = __builtin_amdgcn_mfma_f32_16x16x32_bf16(af, bfr, acc[mt], 0, 0, 0);
        }
    }
    __syncthreads();
    // BN1-fold into Fo[n][o]; D: col = n_local = lo, row = kg*4 + r
#pragma unroll
    for (int mt = 0; mt < 4; ++mt) {
        const int ob = w * 64 + mt * 16 + kg * 4;
        const f32x4 sv = *(const f32x4*)(&s1[ob]);
        const f32x4 bv = *(const f32x4*)(&b1[ob]);
        f32x4 r;
#pragma unroll
        for (int j = 0; j < 4; ++j) r[j] = fmaf(acc[mt][j], sv[j], bv[j]);
        *(f32x4*)(&Fo[lo][ob]) = r;
    }
    __syncthreads();
    // coalesced store: 16 rows x 1KB
    {
        const int row = t >> 4, c = t & 15;
#pragma unroll
        for (int pass = 0; pass < 4; ++pass) {
            const int col = c * 4 + pass * 64;
            const f32x4 v = *(const f32x4*)(&Fo[row][col]);
            *(f32x4*)(&Fs[((size_t)(b * NPTS + n0 + row)) * 256 + col]) = v;
        }
    }
}

// ---------------- fused: selection + A2 build + GEMM2 + BN2 + max ----------------
__global__ __launch_bounds__(256, 4) void fused_kernel(
    const float* __restrict__ xyz, const float* __restrict__ rot,
    const float* __restrict__ crop, const float* __restrict__ Fs,
    const float* __restrict__ wxs,
    const __bf16* __restrict__ W2b, const float* __restrict__ s2g, const float* __restrict__ b2g,
    float* __restrict__ out) {
    __shared__ __align__(16) __bf16 A2[NSAMP][LDA2];
    __shared__ __align__(16) f32x4 lc[NSAMP];   // local coords of selected rows
    __shared__ int seln[NSAMP];                 // selected row index (backfilled)
    __shared__ int selr[NSAMP];                 // raw selection
    __shared__ unsigned long long msk[16];
    __shared__ int wpre[17];

    // XCD-chunked bijective swizzle (2048 = 8 * 256)
    const int bid = ((int)blockIdx.x & 7) * 256 + ((int)blockIdx.x >> 3);
    const int b = bid >> 10;
    const int p = bid & 1023;
    const int t = threadIdx.x;
    const int l = t & 63, w = t >> 6;
    const int lo = l & 15, kg = l >> 4;

    const float cx = xyz[bid * 3 + 0], cy = xyz[bid * 3 + 1], cz = xyz[bid * 3 + 2];
    float R[9];
#pragma unroll
    for (int j = 0; j < 9; ++j) R[j] = rot[bid * 9 + j];
    const float h0 = 0.5f * crop[bid * 3 + 0];
    const float h1 = 0.5f * crop[bid * 3 + 1];
    const float h2 = 0.5f * crop[bid * 3 + 2];

    // inside mask for all 1024 points
#pragma unroll
    for (int i = 0; i < 4; ++i) {
        const int n = i * 256 + t;
        float l0, l1, l2;
        local_coords(xyz + (size_t)(b * NPTS + n) * 3, cx, cy, cz, R, l0, l1, l2);
        bool ins = (__builtin_fabsf(l0) <= h0) && (__builtin_fabsf(l1) <= h1) &&
                   (__builtin_fabsf(l2) <= h2);
        unsigned long long bal = __ballot(ins);
        if (l == 0) msk[i * 4 + w] = bal;
    }
    __syncthreads();
    // parallel exclusive prefix over 16 mask words (wave 0, shfl scan)
    if (t < 64) {
        const int c = (t < 16) ? __popcll(msk[t]) : 0;
        int sum = c;
#pragma unroll
        for (int d = 1; d < 16; d <<= 1) {
            int v = __shfl_up(sum, d);
            if (t >= d) sum += v;
        }
        if (t < 16) wpre[t] = sum - c;
        if (t == 15) wpre[16] = sum;
    }
    __syncthreads();
    const int cnt = wpre[16];
    // stable first-64 selection
#pragma unroll
    for (int i = 0; i < 4; ++i) {
        const int n = i * 256 + t;
        const unsigned long long wd = msk[n >> 6];
        const int bit = n & 63;
        if ((wd >> bit) & 1ull) {
            int rank = wpre[n >> 6] + __popcll(wd & ((1ull << bit) - 1ull));
            if (rank < NSAMP) selr[rank] = n;
        }
    }
    __syncthreads();
    // coords for selected rows, computed once (cnt >= 1 always: point p is inside its own crop)
    if (t < NSAMP) {
        const int n = (t < cnt) ? selr[t] : selr[0];
        seln[t] = n;
        float l0, l1, l2;
        local_coords(xyz + (size_t)(b * NPTS + n) * 3, cx, cy, cz, R, l0, l1, l2);
        lc[t] = f32x4{l0, l1, l2, 0.f};
    }
    __syncthreads();

    // A2[s][o] = relu(Fs[n_s][o] + lc[s]·wxs[o]) in bf16
    // 32-thread groups share one s per iteration -> each Fs row read as one coalesced 1KB burst
    {
        const int oc = (t & 31) * 8;
        const int sgrp = t >> 5;
        f32x4 wv[8];
#pragma unroll
        for (int j = 0; j < 8; ++j) wv[j] = *(const f32x4*)(&wxs[(oc + j) * 4]);
#pragma unroll
        for (int si = 0; si < 8; ++si) {
            const int s = sgrp * 8 + si;
            const f32x4 cd = lc[s];
            const float* Fr = Fs + ((size_t)(b * NPTS + seln[s])) * 256 + oc;
            const f32x4 f0 = *(const f32x4*)(Fr);
            const f32x4 f1 = *(const f32x4*)(Fr + 4);
            bf16x8 pk;
#pragma unroll
            for (int j = 0; j < 8; ++j) {
                const float fj = (j < 4) ? f0[j] : f1[j - 4];
                const float x = fmaf(cd.x, wv[j].x, fmaf(cd.y, wv[j].y, fmaf(cd.z, wv[j].z, fj)));
                pk[j] = (__bf16)fmaxf(x, 0.f);
            }
            *(bf16x8*)(&A2[s][oc]) = pk;
        }
    }
    __syncthreads();

    // GEMM2: h2[s][o] = sum_k A2[s][k] * W2[o][k]
    f32x4 acc[4][4];
#pragma unroll
    for (int mt = 0; mt < 4; ++mt)
#pragma unroll
        for (int nt = 0; nt < 4; ++nt)
            acc[mt][nt] = f32x4{0.f, 0.f, 0.f, 0.f};

    const int ob = w * 64;
#pragma unroll
    for (int ks = 0; ks < 8; ++ks) {
        const int kk = ks * 32 + kg * 8;
        bf16x8 af[4];
#pragma unroll
        for (int mt = 0; mt < 4; ++mt)
            af[mt] = *(const bf16x8*)(&A2[mt * 16 + lo][kk]);
#pragma unroll
        for (int nt = 0; nt < 4; ++nt) {
            const int o = ob + nt * 16 + lo;
            const bf16x8 bfr = *(const bf16x8*)(&W2b[(size_t)o * 256 + kk]);
#pragma unroll
            for (int mt = 0; mt < 4; ++mt)
                acc[mt][nt] = __builtin_amdgcn_mfma_f32_16x16x32_bf16(af[mt], bfr, acc[mt][nt], 0, 0, 0);
        }
    }

    // BN2 + relu + max over 64 samples + store out[b][o][p]
#pragma unroll
    for (int nt = 0; nt < 4; ++nt) {
        const int o = ob + nt * 16 + lo;
        const float sc = s2g[o], bb = b2g[o];
        float mx = 0.f;  // relu output >= 0
#pragma unroll
        for (int mt = 0; mt < 4; ++mt)
#pragma unroll
            for (int r = 0; r < 4; ++r)
                mx = fmaxf(mx, fmaxf(fmaf(acc[mt][nt][r], sc, bb), 0.f));
        mx = fmaxf(mx, __shfl_xor(mx, 16));
        mx = fmaxf(mx, __shfl_xor(mx, 32));
        if (kg == 0)
            out[(size_t)b * (256 * NPTS) + (size_t)o * NPTS + p] = mx;
    }
}

extern "C" void kernel_launch(void* const* d_in, const int* in_sizes, int n_in,
                              void* d_out, int out_size, void* d_ws, size_t ws_size,
                              hipStream_t stream) {
    (void)in_sizes; (void)n_in; (void)out_size; (void)ws_size;
    const float* xyz   = (const float*)d_in[0];
    const float* feats = (const float*)d_in[1];
    const float* rot   = (const float*)d_in[2];
    const float* crop  = (const float*)d_in[3];
    const float* W1    = (const float*)d_in[4];
    const float* g1    = (const float*)d_in[5];
    const float* be1   = (const float*)d_in[6];
    const float* m1    = (const float*)d_in[7];
    const float* v1    = (const float*)d_in[8];
    const float* W2    = (const float*)d_in[9];
    const float* g2    = (const float*)d_in[10];
    const float* be2   = (const float*)d_in[11];
    const float* m2    = (const float*)d_in[12];
    const float* v2    = (const float*)d_in[13];

    char* ws = (char*)d_ws;
    __bf16* W1f = (__bf16*)(ws + 0);        // 256*512*2  = 262144
    __bf16* W2b = (__bf16*)(ws + 262144);   // 256*256*2  = 131072
    float*  wxs = (float*)(ws + 393216);    // 256*4*4    = 4096
    float*  s1  = (float*)(ws + 397312);
    float*  b1  = (float*)(ws + 398336);
    float*  s2  = (float*)(ws + 399360);
    float*  b2  = (float*)(ws + 400384);
    float*  Fs  = (float*)(ws + 401408);    // 2*1024*256*4 = 2097152

    prep_kernel<<<256, 256, 0, stream>>>(W1, W2, g1, be1, m1, v1, g2, be2, m2, v2,
                                         W1f, W2b, wxs, s1, b1, s2, b2);
    fgemm_kernel<<<128, 256, 0, stream>>>(feats, W1f, s1, b1, Fs);
    fused_kernel<<<2048, 256, 0, stream>>>(xyz, rot, crop, Fs, wxs, W2b, s2, b2,
                                           (float*)d_out);
}

// Round 4
// 45.968 us; speedup vs baseline: 1.8289x; 1.4514x over previous
//
#include <hip/hip_runtime.h>
#include <hip/hip_bf16.h>
#include <math.h>

typedef __attribute__((ext_vector_type(8))) __bf16 bf16x8;
typedef __attribute__((ext_vector_type(4))) __bf16 bf16x4;
typedef __attribute__((ext_vector_type(2))) __bf16 bf16x2;
typedef __attribute__((ext_vector_type(4))) float f32x4;

#define NPTS 1024
#define CIN 512
#define NSAMP 64
#define LDFT 520   // bf16 per Ft row: 512 + 8 pad
#define LDFO 136   // bf16 per Fo row: 128 + 8 pad

// Exact-order f32 local-coords to match numpy ref rounding (no FMA contraction):
__device__ __forceinline__ void local_coords(const float* q, float cx, float cy, float cz,
                                             const float R[9], float& l0, float& l1, float& l2) {
    float d0 = __fsub_rn(q[0], cx);
    float d1 = __fsub_rn(q[1], cy);
    float d2 = __fsub_rn(q[2], cz);
    l0 = __fadd_rn(__fadd_rn(__fmul_rn(d0, R[0]), __fmul_rn(d1, R[3])), __fmul_rn(d2, R[6]));
    l1 = __fadd_rn(__fadd_rn(__fmul_rn(d0, R[1]), __fmul_rn(d1, R[4])), __fmul_rn(d2, R[7]));
    l2 = __fadd_rn(__fadd_rn(__fmul_rn(d0, R[2]), __fmul_rn(d1, R[5])), __fmul_rn(d2, R[8]));
}

// -------- prep: weights->bf16 (W2 re-laid for coalesced GEMM2 loads), BN fold --------
__global__ void prep_kernel(const float* __restrict__ W1, const float* __restrict__ W2,
                            const float* __restrict__ g1, const float* __restrict__ be1,
                            const float* __restrict__ m1, const float* __restrict__ v1,
                            const float* __restrict__ g2, const float* __restrict__ be2,
                            const float* __restrict__ m2, const float* __restrict__ v2,
                            __bf16* __restrict__ W1f, __bf16* __restrict__ W2s,
                            float* __restrict__ wxs,
                            float* __restrict__ s1, float* __restrict__ b1,
                            float* __restrict__ s2, float* __restrict__ b2) {
    const int o = blockIdx.x;
    const int t = threadIdx.x;
    if (t == 0) {
        float sc1 = g1[o] / sqrtf(v1[o] + 1e-5f);
        s1[o] = sc1;
        b1[o] = be1[o] - m1[o] * sc1;
        float sc2 = g2[o] / sqrtf(v2[o] + 1e-5f);
        s2[o] = sc2;
        b2[o] = be2[o] - m2[o] * sc2;
        wxs[o * 4 + 0] = sc1 * W1[o * 515 + 0];
        wxs[o * 4 + 1] = sc1 * W1[o * 515 + 1];
        wxs[o * 4 + 2] = sc1 * W1[o * 515 + 2];
        wxs[o * 4 + 3] = 0.f;
    }
    for (int k = t; k < CIN; k += blockDim.x)
        W1f[o * CIN + k] = (__bf16)W1[o * 515 + 3 + k];
    // W2s[f]: f = ((((w*8+ks)*4+nt)*64)+l)*8 + j ; o2=w*64+nt*16+(l&15), k=ks*32+(l>>4)*8+j
    {
        const int f = o * 256 + t;
        const int j = f & 7;
        const int l = (f >> 3) & 63;
        const int nt = (f >> 9) & 3;
        const int ks = (f >> 11) & 7;
        const int w = (f >> 14) & 3;
        const int o2 = w * 64 + nt * 16 + (l & 15);
        const int k = ks * 32 + ((l >> 4) << 3) + j;
        W2s[f] = (__bf16)W2[o2 * 256 + k];
    }
}

// -------- select: crop test + stable first-64 per (b,p); writes seln[u16] --------
__global__ __launch_bounds__(256) void select_kernel(const float* __restrict__ xyz,
                                                     const float* __restrict__ rot,
                                                     const float* __restrict__ crop,
                                                     unsigned short* __restrict__ seln_g) {
    __shared__ unsigned long long msk[16];
    __shared__ int wpre[17];
    __shared__ int selr[NSAMP];

    const int bid = blockIdx.x;
    const int b = bid >> 10;
    const int t = threadIdx.x;
    const int l = t & 63, w = t >> 6;

    const float cx = xyz[bid * 3 + 0], cy = xyz[bid * 3 + 1], cz = xyz[bid * 3 + 2];
    float R[9];
#pragma unroll
    for (int j = 0; j < 9; ++j) R[j] = rot[bid * 9 + j];
    const float h0 = 0.5f * crop[bid * 3 + 0];
    const float h1 = 0.5f * crop[bid * 3 + 1];
    const float h2 = 0.5f * crop[bid * 3 + 2];

#pragma unroll
    for (int i = 0; i < 4; ++i) {
        const int n = i * 256 + t;
        float l0, l1, l2;
        local_coords(xyz + (size_t)(b * NPTS + n) * 3, cx, cy, cz, R, l0, l1, l2);
        bool ins = (__builtin_fabsf(l0) <= h0) && (__builtin_fabsf(l1) <= h1) &&
                   (__builtin_fabsf(l2) <= h2);
        unsigned long long bal = __ballot(ins);
        if (l == 0) msk[i * 4 + w] = bal;
    }
    __syncthreads();
    if (t < 64) {
        const int c = (t < 16) ? __popcll(msk[t]) : 0;
        int sum = c;
#pragma unroll
        for (int d = 1; d < 16; d <<= 1) {
            int v = __shfl_up(sum, d);
            if (t >= d) sum += v;
        }
        if (t < 16) wpre[t] = sum - c;
        if (t == 15) wpre[16] = sum;
    }
    __syncthreads();
    const int cnt = wpre[16];
#pragma unroll
    for (int i = 0; i < 4; ++i) {
        const int n = i * 256 + t;
        const unsigned long long wd = msk[n >> 6];
        const int bit = n & 63;
        if ((wd >> bit) & 1ull) {
            int rank = wpre[n >> 6] + __popcll(wd & ((1ull << bit) - 1ull));
            if (rank < NSAMP) selr[rank] = n;
        }
    }
    __syncthreads();
    if (t < NSAMP) {
        const int n = (t < cnt) ? selr[t] : selr[0];
        seln_g[bid * NSAMP + t] = (unsigned short)n;
    }
}

// ------- F-GEMM: Fsb[b][n][o] = bf16(s1[o]*(sum_c feats[b][c][n]*W1f[o][c]) + b1[o]) -------
// 256 blocks: b = bid>>7, o-half = (bid>>6)&1, n-tile of 16 = bid&63.
__global__ __launch_bounds__(256) void fgemm_kernel(const float* __restrict__ feats,
                                                    const __bf16* __restrict__ W1f,
                                                    const float* __restrict__ s1,
                                                    const float* __restrict__ b1,
                                                    __bf16* __restrict__ Fsb) {
    __shared__ __align__(16) __bf16 Ft[16][LDFT];  // [n_local][c]
    __shared__ __align__(16) __bf16 Fo[16][LDFO];  // [n_local][o_local] store staging
    const int t = threadIdx.x;
    const int b = blockIdx.x >> 7;
    const int half = (blockIdx.x >> 6) & 1;
    const int n0 = (blockIdx.x & 63) << 4;
    const int l = t & 63, w = t >> 6;
    const int lo = l & 15, kg = l >> 4;

    const float* fb = feats + (size_t)b * (CIN * NPTS) + n0;

    // stage 512 c x 16 n, transposed
    {
        const int n = t & 15;
        const int cq = (t >> 4) * 2;
        for (int i = 0; i < 16; ++i) {
            int c = i * 32 + cq;
            float v0 = fb[(size_t)c * NPTS + n];
            float v1 = fb[(size_t)(c + 1) * NPTS + n];
            bf16x2 pk = {(__bf16)v0, (__bf16)v1};
            *(bf16x2*)(&Ft[n][c]) = pk;
        }
    }
    __syncthreads();

    f32x4 acc[2];
#pragma unroll
    for (int mt = 0; mt < 2; ++mt) acc[mt] = f32x4{0.f, 0.f, 0.f, 0.f};

#pragma unroll
    for (int ks = 0; ks < 16; ++ks) {
        const int kk = ks * 32 + kg * 8;
        const bf16x8 bfr = *(const bf16x8*)(&Ft[lo][kk]);
#pragma unroll
        for (int mt = 0; mt < 2; ++mt) {
            const int o = half * 128 + w * 32 + mt * 16 + lo;
            const bf16x8 af = *(const bf16x8*)(&W1f[(size_t)o * CIN + kk]);
            acc[mt] = __builtin_amdgcn_mfma_f32_16x16x32_bf16(af, bfr, acc[mt], 0, 0, 0);
        }
    }
    __syncthreads();
    // BN1-fold -> bf16, stage; D: col = n_local = lo, row(o_local) = kg*4+r
#pragma unroll
    for (int mt = 0; mt < 2; ++mt) {
        const int ol = w * 32 + mt * 16 + kg * 4;
        const f32x4 sv = *(const f32x4*)(&s1[half * 128 + ol]);
        const f32x4 bv = *(const f32x4*)(&b1[half * 128 + ol]);
        bf16x4 r;
#pragma unroll
        for (int j = 0; j < 4; ++j) r[j] = (__bf16)fmaf(acc[mt][j], sv[j], bv[j]);
        *(bf16x4*)(&Fo[lo][ol]) = r;
    }
    __syncthreads();
    // coalesced store: 16 rows x 256B
    {
        const int row = t >> 4, c = t & 15;
        const bf16x8 v = *(const bf16x8*)(&Fo[row][c * 8]);
        *(bf16x8*)(&Fsb[((size_t)(b * NPTS + n0 + row)) * 256 + half * 128 + c * 8]) = v;
    }
}

// ---------------- fused2: lc + A2 build + GEMM2 + BN2 + max ----------------
__global__ __launch_bounds__(256, 4) void fused_kernel(
    const float* __restrict__ xyz, const float* __restrict__ rot,
    const __bf16* __restrict__ Fsb, const float* __restrict__ wxs,
    const unsigned short* __restrict__ seln_g,
    const __bf16* __restrict__ W2s, const float* __restrict__ s2g, const float* __restrict__ b2g,
    float* __restrict__ out) {
    __shared__ __align__(16) char A2raw[NSAMP * 512];  // bf16[64][256], XOR-swizzled rows
    __shared__ __align__(16) f32x4 lc[NSAMP];
    __shared__ int seln_l[NSAMP];

    // XCD-chunked bijective swizzle (2048 = 8 * 256)
    const int bid = ((int)blockIdx.x & 7) * 256 + ((int)blockIdx.x >> 3);
    const int b = bid >> 10;
    const int p = bid & 1023;
    const int t = threadIdx.x;
    const int l = t & 63, w = t >> 6;
    const int lo = l & 15, kg = l >> 4;

    // wxs weights for this thread's o-chunk (used in A2 build)
    const int oc = (t & 31) * 8;
    f32x4 wv[8];
#pragma unroll
    for (int j = 0; j < 8; ++j) wv[j] = *(const f32x4*)(&wxs[(oc + j) * 4]);

    // phase 0: selected rows + their local coords (t<64)
    if (t < NSAMP) {
        const int n = (int)seln_g[bid * NSAMP + t];
        seln_l[t] = n;
        const float cx = xyz[bid * 3 + 0], cy = xyz[bid * 3 + 1], cz = xyz[bid * 3 + 2];
        float R[9];
#pragma unroll
        for (int j = 0; j < 9; ++j) R[j] = rot[bid * 9 + j];
        float l0, l1, l2;
        local_coords(xyz + (size_t)(b * NPTS + n) * 3, cx, cy, cz, R, l0, l1, l2);
        lc[t] = f32x4{l0, l1, l2, 0.f};
    }
    __syncthreads();

    // phase 1: A2[s][o] = relu(Fsb[n_s][o] + lc[s]·wxs[o]) in bf16, swizzled store
    {
        const int sgrp = t >> 5;
#pragma unroll
        for (int si = 0; si < 8; ++si) {
            const int s = sgrp * 8 + si;
            const f32x4 cd = lc[s];
            const bf16x8 fv = *(const bf16x8*)(&Fsb[((size_t)(b * NPTS + seln_l[s])) * 256 + oc]);
            bf16x8 pk;
#pragma unroll
            for (int j = 0; j < 8; ++j) {
                const float fj = (float)fv[j];
                const float x = fmaf(cd.x, wv[j].x, fmaf(cd.y, wv[j].y, fmaf(cd.z, wv[j].z, fj)));
                pk[j] = (__bf16)fmaxf(x, 0.f);
            }
            *(bf16x8*)(A2raw + s * 512 + ((oc * 2) ^ ((s & 7) << 4))) = pk;
        }
    }
    __syncthreads();

    // phase 2: GEMM2 h2[s][o] = sum_k A2[s][k] * W2[o][k]
    f32x4 acc[4][4];
#pragma unroll
    for (int mt = 0; mt < 4; ++mt)
#pragma unroll
        for (int nt = 0; nt < 4; ++nt)
            acc[mt][nt] = f32x4{0.f, 0.f, 0.f, 0.f};

    const int ob = w * 64;
#pragma unroll
    for (int ks = 0; ks < 8; ++ks) {
        const int kkb = ks * 64 + kg * 16;  // byte offset of this lane's k-slice
        bf16x8 af[4];
#pragma unroll
        for (int mt = 0; mt < 4; ++mt) {
            const int row = mt * 16 + lo;
            af[mt] = *(const bf16x8*)(A2raw + row * 512 + (kkb ^ ((row & 7) << 4)));
        }
#pragma unroll
        for (int nt = 0; nt < 4; ++nt) {
            const bf16x8 bfr = *(const bf16x8*)(&W2s[(size_t)(((w * 8 + ks) * 4 + nt)) * 512 + l * 8]);
#pragma unroll
            for (int mt = 0; mt < 4; ++mt)
                acc[mt][nt] = __builtin_amdgcn_mfma_f32_16x16x32_bf16(af[mt], bfr, acc[mt][nt], 0, 0, 0);
        }
    }

    // BN2 + relu + max over 64 samples + store out[b][o][p]
#pragma unroll
    for (int nt = 0; nt < 4; ++nt) {
        const int o = ob + nt * 16 + lo;
        const float sc = s2g[o], bb = b2g[o];
        float mx = 0.f;
#pragma unroll
        for (int mt = 0; mt < 4; ++mt)
#pragma unroll
            for (int r = 0; r < 4; ++r)
                mx = fmaxf(mx, fmaxf(fmaf(acc[mt][nt][r], sc, bb), 0.f));
        mx = fmaxf(mx, __shfl_xor(mx, 16));
        mx = fmaxf(mx, __shfl_xor(mx, 32));
        if (kg == 0)
            out[(size_t)b * (256 * NPTS) + (size_t)o * NPTS + p] = mx;
    }
}

extern "C" void kernel_launch(void* const* d_in, const int* in_sizes, int n_in,
                              void* d_out, int out_size, void* d_ws, size_t ws_size,
                              hipStream_t stream) {
    (void)in_sizes; (void)n_in; (void)out_size; (void)ws_size;
    const float* xyz   = (const float*)d_in[0];
    const float* feats = (const float*)d_in[1];
    const float* rot   = (const float*)d_in[2];
    const float* crop  = (const float*)d_in[3];
    const float* W1    = (const float*)d_in[4];
    const float* g1    = (const float*)d_in[5];
    const float* be1   = (const float*)d_in[6];
    const float* m1    = (const float*)d_in[7];
    const float* v1    = (const float*)d_in[8];
    const float* W2    = (const float*)d_in[9];
    const float* g2    = (const float*)d_in[10];
    const float* be2   = (const float*)d_in[11];
    const float* m2    = (const float*)d_in[12];
    const float* v2    = (const float*)d_in[13];

    char* ws = (char*)d_ws;
    __bf16* W1f = (__bf16*)(ws + 0);            // 256*512*2  = 262144
    __bf16* W2s = (__bf16*)(ws + 262144);       // 256*256*2  = 131072
    float*  wxs = (float*)(ws + 393216);        // 4096
    float*  s1  = (float*)(ws + 397312);
    float*  b1  = (float*)(ws + 398336);
    float*  s2  = (float*)(ws + 399360);
    float*  b2  = (float*)(ws + 400384);
    __bf16* Fsb = (__bf16*)(ws + 401408);       // 2*1024*256*2 = 1048576
    unsigned short* seln = (unsigned short*)(ws + 1449984);  // 2048*64*2 = 262144

    prep_kernel<<<256, 256, 0, stream>>>(W1, W2, g1, be1, m1, v1, g2, be2, m2, v2,
                                         W1f, W2s, wxs, s1, b1, s2, b2);
    select_kernel<<<2048, 256, 0, stream>>>(xyz, rot, crop, seln);
    fgemm_kernel<<<256, 256, 0, stream>>>(feats, W1f, s1, b1, Fsb);
    fused_kernel<<<2048, 256, 0, stream>>>(xyz, rot, Fsb, wxs, seln, W2s, s2, b2,
                                           (float*)d_out);
}

// Round 5
// 44.047 us; speedup vs baseline: 1.9086x; 1.0436x over previous
//
#include <hip/hip_runtime.h>
#include <hip/hip_bf16.h>
#include <math.h>

typedef __attribute__((ext_vector_type(8))) __bf16 bf16x8;
typedef __attribute__((ext_vector_type(4))) __bf16 bf16x4;
typedef __attribute__((ext_vector_type(2))) __bf16 bf16x2;
typedef __attribute__((ext_vector_type(4))) float f32x4;

#define NPTS 1024
#define CIN 512
#define NSAMP 64
#define LDFT 520   // bf16 per Ft row: 512 + 8 pad
#define LDFO 136   // bf16 per Fo row: 128 + 8 pad

// Exact-order f32 local-coords to match numpy ref rounding (no FMA contraction):
__device__ __forceinline__ void local_coords(const float* q, float cx, float cy, float cz,
                                             const float R[9], float& l0, float& l1, float& l2) {
    float d0 = __fsub_rn(q[0], cx);
    float d1 = __fsub_rn(q[1], cy);
    float d2 = __fsub_rn(q[2], cz);
    l0 = __fadd_rn(__fadd_rn(__fmul_rn(d0, R[0]), __fmul_rn(d1, R[3])), __fmul_rn(d2, R[6]));
    l1 = __fadd_rn(__fadd_rn(__fmul_rn(d0, R[1]), __fmul_rn(d1, R[4])), __fmul_rn(d2, R[7]));
    l2 = __fadd_rn(__fadd_rn(__fmul_rn(d0, R[2]), __fmul_rn(d1, R[5])), __fmul_rn(d2, R[8]));
}

// -------- setup: blocks [0,256) = prep (weights->bf16, BN fold, W2 re-layout);
//                 blocks [256,2304) = select (crop test + stable first-64) --------
__global__ __launch_bounds__(256) void setup_kernel(
    const float* __restrict__ xyz, const float* __restrict__ rot,
    const float* __restrict__ crop,
    const float* __restrict__ W1, const float* __restrict__ W2,
    const float* __restrict__ g1, const float* __restrict__ be1,
    const float* __restrict__ m1, const float* __restrict__ v1,
    const float* __restrict__ g2, const float* __restrict__ be2,
    const float* __restrict__ m2, const float* __restrict__ v2,
    __bf16* __restrict__ W1f, __bf16* __restrict__ W2s,
    float* __restrict__ wxs,
    float* __restrict__ s1, float* __restrict__ b1,
    float* __restrict__ s2, float* __restrict__ b2,
    unsigned short* __restrict__ seln_g) {
    __shared__ unsigned long long msk[16];
    __shared__ int wpre[17];
    __shared__ int selr[NSAMP];

    const int t = threadIdx.x;
    if (blockIdx.x < 256) {
        // ---- prep role ----
        const int o = blockIdx.x;
        if (t == 0) {
            float sc1 = g1[o] / sqrtf(v1[o] + 1e-5f);
            s1[o] = sc1;
            b1[o] = be1[o] - m1[o] * sc1;
            float sc2 = g2[o] / sqrtf(v2[o] + 1e-5f);
            s2[o] = sc2;
            b2[o] = be2[o] - m2[o] * sc2;
            wxs[o * 4 + 0] = sc1 * W1[o * 515 + 0];
            wxs[o * 4 + 1] = sc1 * W1[o * 515 + 1];
            wxs[o * 4 + 2] = sc1 * W1[o * 515 + 2];
            wxs[o * 4 + 3] = 0.f;
        }
        for (int k = t; k < CIN; k += blockDim.x)
            W1f[o * CIN + k] = (__bf16)W1[o * 515 + 3 + k];
        // W2s[f]: f = ((((w*8+ks)*2+nt)*64)+l)*8 + j
        //   o2 = w*32 + nt*16 + (l&15);  k = ks*32 + (l>>4)*8 + j
        {
            const int f = o * 256 + t;
            const int j = f & 7;
            const int l = (f >> 3) & 63;
            const int nt = (f >> 9) & 1;
            const int ks = (f >> 10) & 7;
            const int w = (f >> 13) & 7;
            const int o2 = w * 32 + nt * 16 + (l & 15);
            const int k = ks * 32 + ((l >> 4) << 3) + j;
            W2s[f] = (__bf16)W2[o2 * 256 + k];
        }
        return;
    }
    // ---- select role ----
    const int bid = blockIdx.x - 256;
    const int b = bid >> 10;
    const int l = t & 63, w = t >> 6;

    const float cx = xyz[bid * 3 + 0], cy = xyz[bid * 3 + 1], cz = xyz[bid * 3 + 2];
    float R[9];
#pragma unroll
    for (int j = 0; j < 9; ++j) R[j] = rot[bid * 9 + j];
    const float h0 = 0.5f * crop[bid * 3 + 0];
    const float h1 = 0.5f * crop[bid * 3 + 1];
    const float h2 = 0.5f * crop[bid * 3 + 2];

#pragma unroll
    for (int i = 0; i < 4; ++i) {
        const int n = i * 256 + t;
        float l0, l1, l2;
        local_coords(xyz + (size_t)(b * NPTS + n) * 3, cx, cy, cz, R, l0, l1, l2);
        bool ins = (__builtin_fabsf(l0) <= h0) && (__builtin_fabsf(l1) <= h1) &&
                   (__builtin_fabsf(l2) <= h2);
        unsigned long long bal = __ballot(ins);
        if (l == 0) msk[i * 4 + w] = bal;
    }
    __syncthreads();
    if (t < 64) {
        const int c = (t < 16) ? __popcll(msk[t]) : 0;
        int sum = c;
#pragma unroll
        for (int d = 1; d < 16; d <<= 1) {
            int v = __shfl_up(sum, d);
            if (t >= d) sum += v;
        }
        if (t < 16) wpre[t] = sum - c;
        if (t == 15) wpre[16] = sum;
    }
    __syncthreads();
    const int cnt = wpre[16];
#pragma unroll
    for (int i = 0; i < 4; ++i) {
        const int n = i * 256 + t;
        const unsigned long long wd = msk[n >> 6];
        const int bit = n & 63;
        if ((wd >> bit) & 1ull) {
            int rank = wpre[n >> 6] + __popcll(wd & ((1ull << bit) - 1ull));
            if (rank < NSAMP) selr[rank] = n;
        }
    }
    __syncthreads();
    if (t < NSAMP) {
        const int n = (t < cnt) ? selr[t] : selr[0];  // cnt>=1: p is inside its own crop
        seln_g[(size_t)bid * NSAMP + t] = (unsigned short)n;
    }
}

// ------- F-GEMM: Fsb[b][n][o] = bf16(s1[o]*(sum_c feats[b][c][n]*W1f[o][c]) + b1[o]) -------
__global__ __launch_bounds__(256) void fgemm_kernel(const float* __restrict__ feats,
                                                    const __bf16* __restrict__ W1f,
                                                    const float* __restrict__ s1,
                                                    const float* __restrict__ b1,
                                                    __bf16* __restrict__ Fsb) {
    __shared__ __align__(16) __bf16 Ft[16][LDFT];
    __shared__ __align__(16) __bf16 Fo[16][LDFO];
    const int t = threadIdx.x;
    const int b = blockIdx.x >> 7;
    const int half = (blockIdx.x >> 6) & 1;
    const int n0 = (blockIdx.x & 63) << 4;
    const int l = t & 63, w = t >> 6;
    const int lo = l & 15, kg = l >> 4;

    const float* fb = feats + (size_t)b * (CIN * NPTS) + n0;

    {
        const int n = t & 15;
        const int cq = (t >> 4) * 2;
        for (int i = 0; i < 16; ++i) {
            int c = i * 32 + cq;
            float v0 = fb[(size_t)c * NPTS + n];
            float v1 = fb[(size_t)(c + 1) * NPTS + n];
            bf16x2 pk = {(__bf16)v0, (__bf16)v1};
            *(bf16x2*)(&Ft[n][c]) = pk;
        }
    }
    __syncthreads();

    f32x4 acc[2];
#pragma unroll
    for (int mt = 0; mt < 2; ++mt) acc[mt] = f32x4{0.f, 0.f, 0.f, 0.f};

#pragma unroll
    for (int ks = 0; ks < 16; ++ks) {
        const int kk = ks * 32 + kg * 8;
        const bf16x8 bfr = *(const bf16x8*)(&Ft[lo][kk]);
#pragma unroll
        for (int mt = 0; mt < 2; ++mt) {
            const int o = half * 128 + w * 32 + mt * 16 + lo;
            const bf16x8 af = *(const bf16x8*)(&W1f[(size_t)o * CIN + kk]);
            acc[mt] = __builtin_amdgcn_mfma_f32_16x16x32_bf16(af, bfr, acc[mt], 0, 0, 0);
        }
    }
    __syncthreads();
#pragma unroll
    for (int mt = 0; mt < 2; ++mt) {
        const int ol = w * 32 + mt * 16 + kg * 4;
        const f32x4 sv = *(const f32x4*)(&s1[half * 128 + ol]);
        const f32x4 bv = *(const f32x4*)(&b1[half * 128 + ol]);
        bf16x4 r;
#pragma unroll
        for (int j = 0; j < 4; ++j) r[j] = (__bf16)fmaf(acc[mt][j], sv[j], bv[j]);
        *(bf16x4*)(&Fo[lo][ol]) = r;
    }
    __syncthreads();
    {
        const int row = t >> 4, c = t & 15;
        const bf16x8 v = *(const bf16x8*)(&Fo[row][c * 8]);
        *(bf16x8*)(&Fsb[((size_t)(b * NPTS + n0 + row)) * 256 + half * 128 + c * 8]) = v;
    }
}

// -------- fused: weight-stationary GEMM2 over P=4 p-values per block --------
// 512 threads = 8 waves; wave w owns o in [32w, 32w+32) (nt 0..1).
__global__ __launch_bounds__(512, 2) void fused_kernel(
    const float* __restrict__ xyz, const float* __restrict__ rot,
    const __bf16* __restrict__ Fsb, const float* __restrict__ wxs,
    const unsigned short* __restrict__ seln_g,
    const __bf16* __restrict__ W2s, const float* __restrict__ s2g, const float* __restrict__ b2g,
    float* __restrict__ out) {
    __shared__ __align__(16) char A2raw[NSAMP * 512];  // bf16[64][256], XOR-swizzled
    __shared__ __align__(16) f32x4 lcb[NSAMP];
    __shared__ __align__(16) float outst[256][4];

    // XCD-chunked bijective swizzle over 512 = 8 * 64 p-groups
    const int raw = (int)blockIdx.x;
    const int pg = (raw & 7) * 64 + (raw >> 3);
    const int b = pg >> 8;
    const int p0 = (pg & 255) * 4;
    const int t = threadIdx.x;
    const int l = t & 63, w = t >> 6;
    const int lo = l & 15, kg = l >> 4;

    // --- W2 fragments: resident in registers for the whole block ---
    bf16x8 wf[8][2];
#pragma unroll
    for (int ks = 0; ks < 8; ++ks)
#pragma unroll
        for (int nt = 0; nt < 2; ++nt)
            wf[ks][nt] = *(const bf16x8*)(&W2s[(size_t)((((w * 8 + ks) * 2 + nt) * 64) + l) * 8]);

    // A2-build mapping: o-chunk of 8, 4 s-rows per thread
    const int oc = (t & 31) * 8;
    const int sg = t >> 5;  // 0..15
    f32x4 wv[8];
#pragma unroll
    for (int j = 0; j < 8; ++j) wv[j] = *(const f32x4*)(&wxs[(oc + j) * 4]);

    // BN2 params (p-invariant)
    float sc[2], bb[2];
#pragma unroll
    for (int nt = 0; nt < 2; ++nt) {
        const int o = w * 32 + nt * 16 + lo;
        sc[nt] = s2g[o];
        bb[nt] = b2g[o];
    }

    bf16x8 stg[4];

    // ---- prologue: stage + build A2 for p0 ----
    {
        const int p = p0;
        if (t < NSAMP) {
            const int n = (int)seln_g[((size_t)(b * NPTS + p)) * 64 + t];
            const int bid = b * NPTS + p;
            const float cx = xyz[bid * 3 + 0], cy = xyz[bid * 3 + 1], cz = xyz[bid * 3 + 2];
            float R[9];
#pragma unroll
            for (int j = 0; j < 9; ++j) R[j] = rot[bid * 9 + j];
            float l0, l1, l2;
            local_coords(xyz + (size_t)(b * NPTS + n) * 3, cx, cy, cz, R, l0, l1, l2);
            lcb[t] = f32x4{l0, l1, l2, 0.f};
        }
#pragma unroll
        for (int si = 0; si < 4; ++si) {
            const int s = sg * 4 + si;
            const int n = (int)seln_g[((size_t)(b * NPTS + p)) * 64 + s];
            stg[si] = *(const bf16x8*)(&Fsb[((size_t)(b * NPTS + n)) * 256 + oc]);
        }
        __syncthreads();
#pragma unroll
        for (int si = 0; si < 4; ++si) {
            const int s = sg * 4 + si;
            const f32x4 cd = lcb[s];
            bf16x8 pk;
#pragma unroll
            for (int j = 0; j < 8; ++j) {
                const float x = fmaf(cd.x, wv[j].x,
                                     fmaf(cd.y, wv[j].y, fmaf(cd.z, wv[j].z, (float)stg[si][j])));
                pk[j] = (__bf16)fmaxf(x, 0.f);
            }
            *(bf16x8*)(A2raw + s * 512 + ((oc * 2) ^ ((s & 7) << 4))) = pk;
        }
        __syncthreads();
    }

    // ---- main loop over the 4 p-values ----
    for (int pi = 0; pi < 4; ++pi) {
        // issue-early: stage p_{pi+1} (gathers into regs; wave0 computes lc)
        if (pi < 3) {
            const int p = p0 + pi + 1;
            if (t < NSAMP) {
                const int n = (int)seln_g[((size_t)(b * NPTS + p)) * 64 + t];
                const int bid = b * NPTS + p;
                const float cx = xyz[bid * 3 + 0], cy = xyz[bid * 3 + 1], cz = xyz[bid * 3 + 2];
                float R[9];
#pragma unroll
                for (int j = 0; j < 9; ++j) R[j] = rot[bid * 9 + j];
                float l0, l1, l2;
                local_coords(xyz + (size_t)(b * NPTS + n) * 3, cx, cy, cz, R, l0, l1, l2);
                lcb[t] = f32x4{l0, l1, l2, 0.f};
            }
#pragma unroll
            for (int si = 0; si < 4; ++si) {
                const int s = sg * 4 + si;
                const int n = (int)seln_g[((size_t)(b * NPTS + p)) * 64 + s];
                stg[si] = *(const bf16x8*)(&Fsb[((size_t)(b * NPTS + n)) * 256 + oc]);
            }
        }

        // GEMM2 on current A2 (W2 from registers)
        f32x4 acc[4][2];
#pragma unroll
        for (int mt = 0; mt < 4; ++mt)
#pragma unroll
            for (int nt = 0; nt < 2; ++nt)
                acc[mt][nt] = f32x4{0.f, 0.f, 0.f, 0.f};

#pragma unroll
        for (int ks = 0; ks < 8; ++ks) {
            const int kkb = ks * 64 + kg * 16;
            bf16x8 af[4];
#pragma unroll
            for (int mt = 0; mt < 4; ++mt) {
                const int row = mt * 16 + lo;
                af[mt] = *(const bf16x8*)(A2raw + row * 512 + (kkb ^ ((row & 7) << 4)));
            }
#pragma unroll
            for (int nt = 0; nt < 2; ++nt)
#pragma unroll
                for (int mt = 0; mt < 4; ++mt)
                    acc[mt][nt] = __builtin_amdgcn_mfma_f32_16x16x32_bf16(af[mt], wf[ks][nt],
                                                                          acc[mt][nt], 0, 0, 0);
        }

        // BN2 + relu + max over s, stash per-p column
#pragma unroll
        for (int nt = 0; nt < 2; ++nt) {
            float mx = 0.f;
#pragma unroll
            for (int mt = 0; mt < 4; ++mt)
#pragma unroll
                for (int r = 0; r < 4; ++r)
                    mx = fmaxf(mx, fmaxf(fmaf(acc[mt][nt][r], sc[nt], bb[nt]), 0.f));
            mx = fmaxf(mx, __shfl_xor(mx, 16));
            mx = fmaxf(mx, __shfl_xor(mx, 32));
            if (kg == 0) outst[w * 32 + nt * 16 + lo][pi] = mx;
        }
        __syncthreads();  // BAR1: GEMM2 reads done; lcb ready for build

        if (pi < 3) {
#pragma unroll
            for (int si = 0; si < 4; ++si) {
                const int s = sg * 4 + si;
                const f32x4 cd = lcb[s];
                bf16x8 pk;
#pragma unroll
                for (int j = 0; j < 8; ++j) {
                    const float x = fmaf(cd.x, wv[j].x,
                                         fmaf(cd.y, wv[j].y, fmaf(cd.z, wv[j].z, (float)stg[si][j])));
                    pk[j] = (__bf16)fmaxf(x, 0.f);
                }
                *(bf16x8*)(A2raw + s * 512 + ((oc * 2) ^ ((s & 7) << 4))) = pk;
            }
        }
        __syncthreads();  // BAR2: A2 writes visible
    }

    // coalesced output: out[b][o][p0..p0+3] as one f32x4 per o
    if (t < 256) {
        const int o = t;
        const f32x4 v = *(const f32x4*)(&outst[o][0]);
        *(f32x4*)(&out[((size_t)b * 256 + o) * NPTS + p0]) = v;
    }
}

extern "C" void kernel_launch(void* const* d_in, const int* in_sizes, int n_in,
                              void* d_out, int out_size, void* d_ws, size_t ws_size,
                              hipStream_t stream) {
    (void)in_sizes; (void)n_in; (void)out_size; (void)ws_size;
    const float* xyz   = (const float*)d_in[0];
    const float* feats = (const float*)d_in[1];
    const float* rot   = (const float*)d_in[2];
    const float* crop  = (const float*)d_in[3];
    const float* W1    = (const float*)d_in[4];
    const float* g1    = (const float*)d_in[5];
    const float* be1   = (const float*)d_in[6];
    const float* m1    = (const float*)d_in[7];
    const float* v1    = (const float*)d_in[8];
    const float* W2    = (const float*)d_in[9];
    const float* g2    = (const float*)d_in[10];
    const float* be2   = (const float*)d_in[11];
    const float* m2    = (const float*)d_in[12];
    const float* v2    = (const float*)d_in[13];

    char* ws = (char*)d_ws;
    __bf16* W1f = (__bf16*)(ws + 0);            // 262144
    __bf16* W2s = (__bf16*)(ws + 262144);       // 131072
    float*  wxs = (float*)(ws + 393216);        // 4096
    float*  s1  = (float*)(ws + 397312);
    float*  b1  = (float*)(ws + 398336);
    float*  s2  = (float*)(ws + 399360);
    float*  b2  = (float*)(ws + 400384);
    __bf16* Fsb = (__bf16*)(ws + 401408);       // 1048576
    unsigned short* seln = (unsigned short*)(ws + 1449984);  // 262144

    setup_kernel<<<2304, 256, 0, stream>>>(xyz, rot, crop,
                                           W1, W2, g1, be1, m1, v1, g2, be2, m2, v2,
                                           W1f, W2s, wxs, s1, b1, s2, b2, seln);
    fgemm_kernel<<<256, 256, 0, stream>>>(feats, W1f, s1, b1, Fsb);
    fused_kernel<<<512, 512, 0, stream>>>(xyz, rot, Fsb, wxs, seln, W2s, s2, b2,
                                          (float*)d_out);
}